// Round 15
// baseline (355.084 us; speedup 1.0000x reference)
//
#include <hip/hip_runtime.h>
#include <math.h>

#define T_TOK 8192
#define HD    2048
#define NE    8
#define BM    128
#define BN    128
#define NT    (HD / 64)      // 32 K-tiles
#define MAXT  136            // max row-tiles: 16384/128 + 8 pad tiles
#define RMAX  17408          // 136 * 128

typedef __bf16 bf16x4 __attribute__((ext_vector_type(4)));
typedef __bf16 bf16x8 __attribute__((ext_vector_type(8)));
typedef float  f32x4  __attribute__((ext_vector_type(4)));

// 16B async global->LDS. LDS dest is wave-uniform base + lane*16 (linear);
// per-lane GLOBAL source carries the swizzle (rule 21).
#define GLOAD16(src, dst)                                                              \
    __builtin_amdgcn_global_load_lds((__attribute__((address_space(1))) void*)(src),   \
                                     (__attribute__((address_space(3))) void*)(dst),   \
                                     16, 0, 0)

// compile-time memory-order fence: pins load-issue groups for the vmcnt ledger
#define MEMFENCE() asm volatile("" ::: "memory")

// ---------------------------------------------------------------------------
// Router + x->bf16 + expert histogram fused.
// ---------------------------------------------------------------------------
__global__ __launch_bounds__(256) void router_cvt_kernel(
    const float* __restrict__ x, const float* __restrict__ Wg,
    const float* __restrict__ bg, float* __restrict__ logits_out,
    int* __restrict__ tok_exp, float* __restrict__ tok_w,
    __bf16* __restrict__ xb, int* __restrict__ cnt)
{
    __shared__ int hbin[NE];
    const int lane = threadIdx.x & 63;
    const int wv   = threadIdx.x >> 6;
    const int t    = blockIdx.x * 4 + wv;
    const float* xr  = x  + (size_t)t * HD;
    __bf16*      xbr = xb + (size_t)t * HD;

    if (threadIdx.x < NE) hbin[threadIdx.x] = 0;
    __syncthreads();

    float acc[8] = {0.f,0.f,0.f,0.f,0.f,0.f,0.f,0.f};
#pragma unroll
    for (int j = 0; j < 8; ++j) {
        const int h0 = j * 256 + lane * 4;
        float4 xv = *reinterpret_cast<const float4*>(xr + h0);
        bf16x4 bv;
        bv[0] = (__bf16)xv.x; bv[1] = (__bf16)xv.y;
        bv[2] = (__bf16)xv.z; bv[3] = (__bf16)xv.w;
        *reinterpret_cast<bf16x4*>(xbr + h0) = bv;

        const float4* wg = reinterpret_cast<const float4*>(Wg + (size_t)h0 * NE);
        float xs[4] = {xv.x, xv.y, xv.z, xv.w};
#pragma unroll
        for (int r = 0; r < 4; ++r) {
            float4 wa = wg[r * 2], wb = wg[r * 2 + 1];
            acc[0] += xs[r] * wa.x; acc[1] += xs[r] * wa.y;
            acc[2] += xs[r] * wa.z; acc[3] += xs[r] * wa.w;
            acc[4] += xs[r] * wb.x; acc[5] += xs[r] * wb.y;
            acc[6] += xs[r] * wb.z; acc[7] += xs[r] * wb.w;
        }
    }
#pragma unroll
    for (int off = 32; off; off >>= 1) {
#pragma unroll
        for (int e = 0; e < 8; ++e) acc[e] += __shfl_xor(acc[e], off);
    }
    if (lane == 0) {
        float lg[8];
#pragma unroll
        for (int e = 0; e < 8; ++e) lg[e] = acc[e] + bg[e];
        float4* lo = reinterpret_cast<float4*>(logits_out + (size_t)t * NE);
        lo[0] = make_float4(lg[0], lg[1], lg[2], lg[3]);
        lo[1] = make_float4(lg[4], lg[5], lg[6], lg[7]);
        int i0 = 0;
        for (int e = 1; e < 8; ++e) if (lg[e] > lg[i0]) i0 = e;
        int i1 = (i0 == 0) ? 1 : 0;
        for (int e = 0; e < 8; ++e) if (e != i0 && lg[e] > lg[i1]) i1 = e;
        float d = expf(lg[i1] - lg[i0]);
        float inv = 1.0f / (1.0f + d);
        tok_exp[t * 2]     = i0;
        tok_exp[t * 2 + 1] = i1;
        tok_w[t * 2]       = inv;
        tok_w[t * 2 + 1]   = d * inv;
        atomicAdd(&hbin[i0], 1);
        atomicAdd(&hbin[i1], 1);
    }
    __syncthreads();
    if (threadIdx.x < NE && hbin[threadIdx.x] > 0)
        atomicAdd(&cnt[threadIdx.x], hbin[threadIdx.x]);
}

// ---------------------------------------------------------------------------
// W[e][k][f] fp32 -> FRAGMENT-MAJOR bf16 Wt2: 1KB fragments [e][fb][kb] where
// lane l's 16B = B[col=fb*16+(l&15)][k=kb*32+(l>>4)*8 .. +8], B[col][k] =
// W[e][k][col]. GEMM then loads each B-operand as ONE coalesced 1KB
// global_load_dwordx4 straight to VGPRs (no LDS for B).
// Same padded-LDS transpose as before; only output addressing changes.
// ---------------------------------------------------------------------------
__global__ __launch_bounds__(256) void wt2_kernel(const float* __restrict__ W,
                                                  __bf16* __restrict__ Wt2)
{
    const int e  = blockIdx.z;
    const int k0 = blockIdx.y * 64;
    const int f0 = blockIdx.x * 64;
    __shared__ float T[64][65];

    const int t  = threadIdx.x;
    const int fi = (t & 15) * 4;
    const int kb = t >> 4;
    const float* src = W + (size_t)e * HD * HD + (size_t)(k0 + kb) * HD + f0 + fi;
#pragma unroll
    for (int j = 0; j < 4; ++j) {
        float4 v = *reinterpret_cast<const float4*>(src + (size_t)j * 16 * HD);
        int k = kb + j * 16;
        T[k][fi + 0] = v.x;
        T[k][fi + 1] = v.y;
        T[k][fi + 2] = v.z;
        T[k][fi + 3] = v.w;
    }
    __syncthreads();
    const int f  = t >> 2;            // 0..63
    const int c0 = (t & 3) * 2;       // first of 2 output 8-elem chunks
    const int kc = c0 * 8;
    bf16x8 o0, o1;
#pragma unroll
    for (int j = 0; j < 8; ++j) o0[j] = (__bf16)T[kc + j][f];
#pragma unroll
    for (int j = 0; j < 8; ++j) o1[j] = (__bf16)T[kc + 8 + j][f];

    // chunk ch holds k = k0 + ch*8 .. +8 at col = f0 + f.
    // fragment: fb = (f0+f)>>4, kbo = k0/32 + (ch>>2), lane = (f&15) + ((ch&3)<<4)
    const int fb = (f0 >> 4) + (f >> 4);
#pragma unroll
    for (int j = 0; j < 2; ++j) {
        const int ch   = c0 + j;
        const int kbo  = (k0 >> 5) + (ch >> 2);
        const int lane = (f & 15) + ((ch & 3) << 4);
        size_t off = ((size_t)e << 22) + ((size_t)fb << 15) + ((size_t)kbo << 9)
                   + ((size_t)lane << 3);
        *reinterpret_cast<bf16x8*>(Wt2 + off) = (j == 0) ? o0 : o1;
    }
}

// ---------------------------------------------------------------------------
// Scan: per-expert offsets padded to 128, tile table, init cursors.
// ---------------------------------------------------------------------------
__global__ void scan_kernel(const int* __restrict__ cnt, int* __restrict__ cursor,
                            int* __restrict__ tile_exp, int* __restrict__ tile_row0,
                            int* __restrict__ ntiles)
{
    if (threadIdx.x == 0) {
        int off = 0, nt = 0;
        for (int e = 0; e < NE; ++e) {
            cursor[e] = off;
            int c = cnt[e];
            int tiles = (c + 127) >> 7;
            for (int i = 0; i < tiles; ++i) {
                tile_exp[nt]  = e;
                tile_row0[nt] = off + (i << 7);
                ++nt;
            }
            off += tiles << 7;
        }
        *ntiles = nt;
    }
}

// ---------------------------------------------------------------------------
// Scatter: per-block LDS ranks + ONE cursor reservation per expert per block.
// ---------------------------------------------------------------------------
__global__ __launch_bounds__(256) void scatter_kernel(
    const int* __restrict__ tok_exp, const float* __restrict__ tok_w,
    int* __restrict__ cursor, int* __restrict__ row_token, float* __restrict__ row_coef)
{
    __shared__ int lcnt[NE];
    __shared__ int lbase[NE];
    const int tid = threadIdx.x;
    if (tid < NE) lcnt[tid] = 0;
    __syncthreads();
    const int s = blockIdx.x * 256 + tid;
    const int e = tok_exp[s];
    const int r = atomicAdd(&lcnt[e], 1);          // LDS atomic (fast)
    __syncthreads();
    if (tid < NE) lbase[tid] = atomicAdd(&cursor[tid], lcnt[tid]);
    __syncthreads();
    const int pos = lbase[e] + r;
    row_token[pos] = s >> 1;                        // slot -> token
    row_coef[pos]  = tok_w[s];
}

// ---------------------------------------------------------------------------
// Grouped GEMM R15: 128x128 tile, BK=64, 4 waves (2x2). A in LDS (dbuf
// 2x16KB); B loaded as pre-tiled 1KB fragments global->VGPR (one coalesced
// dwordx4/wave per fragment — fixes R11's 16-scattered-request failure).
// LDS traffic per block-K-step 96->48KB; LDS 32KB -> target 3 blocks/CU.
// Ledger (issue order B(t+1) then A(t+2) per step; in-order retirement):
//   prologue: A(0) 4 gload_lds, B(0) 8 loads, A(1) 4.
//   step t wait: newest in flight = A(t+1) 4 -> vmcnt(4) retires A(t),B(t).
//   tail t=NT-1: vmcnt(0). t=NT-2 issues B(NT-1) only (reg-private, no
//   barrier needed). breg parity is compile-time (hand-unrolled K_STEP).
// ---------------------------------------------------------------------------
__global__ __launch_bounds__(256, 3) void moe_gemm_128(
    const __bf16* __restrict__ xb, const __bf16* __restrict__ Wt2,
    const float* __restrict__ bexp,
    const int* __restrict__ tile_exp, const int* __restrict__ tile_row0,
    const int* __restrict__ ntiles_p, const int* __restrict__ row_token,
    const float* __restrict__ row_coef, float* __restrict__ out)
{
    const int rt = blockIdx.y;
    if (rt >= *ntiles_p) return;
    const int e  = tile_exp[rt];
    const int r0 = tile_row0[rt];
    const int cb = blockIdx.x * BN;

    // A only: parity p at p*16384, [128][64]bf16 (swizzled-source linear)
    __shared__ __align__(16) char lds[32768];

    const int tid  = threadIdx.x;
    const int lane = tid & 63;
    const int wv   = tid >> 6;          // 0..3
    const int wr   = (wv >> 1) * 64;    // wave row base
    const int wc   = (wv & 1) * 64;     // wave col base

    // A staging: source column pre-swizzled (rule 21)
    const int colS = ((((tid & 7) * 16) ^ (((tid >> 3) & 7) << 4))) >> 1;  // bf16 elems

    const __bf16* srcA[4];
#pragma unroll
    for (int i = 0; i < 4; ++i) {
        int gr  = i * 32 + (tid >> 3);
        int tok = row_token[r0 + gr];
        if (tok < 0) tok = 0;           // pad rows: arbitrary data, discarded later
        srcA[i] = xb + (size_t)tok * HD + colS;
    }

    // B fragment base: fb = (cb+wc)/16 (+n), kb = 2t+ks; 1KB per fragment
    const __bf16* bptr = Wt2 + ((size_t)e << 22)
                       + ((size_t)((cb + wc) >> 4) << 15) + ((size_t)lane << 3);

    f32x4 acc[4][4];
#pragma unroll
    for (int m = 0; m < 4; ++m)
#pragma unroll
        for (int n = 0; n < 4; ++n) acc[m][n] = (f32x4){0.f, 0.f, 0.f, 0.f};

    const int fr    = lane & 15;
    const int swz   = (lane & 7) << 4;
    const int koff0 = (((lane >> 4) * 16)      ) ^ swz;   // A ks=0 k-byte, swizzled
    const int koff1 = (((lane >> 4) * 16) + 64 ) ^ swz;   // A ks=1

    bf16x8 breg[2][4][2];               // [parity][n][ks] — parity is literal below

    // prologue: A(0), B(0), A(1)  (issue groups pinned by fences)
    {
        char* d0 = lds + wv * 1024;
        char* d1 = d0 + 16384;
#pragma unroll
        for (int i = 0; i < 4; ++i) GLOAD16(srcA[i], d0 + i * 4096);
        MEMFENCE();
#pragma unroll
        for (int n = 0; n < 4; ++n)
#pragma unroll
            for (int ks = 0; ks < 2; ++ks)
                breg[0][n][ks] = *reinterpret_cast<const bf16x8*>(
                    bptr + ((size_t)n << 15) + ((size_t)ks << 9));
        MEMFENCE();
#pragma unroll
        for (int i = 0; i < 4; ++i) GLOAD16(srcA[i] + 64, d1 + i * 4096);
        MEMFENCE();
    }

#define K_STEP(T, P)                                                                    \
    {                                                                                   \
        if ((T) < NT - 1) { asm volatile("s_waitcnt vmcnt(4)" ::: "memory"); }          \
        else              { asm volatile("s_waitcnt vmcnt(0)" ::: "memory"); }          \
        __builtin_amdgcn_s_barrier();                                                   \
        const char* ab = lds + (P) * 16384;                                             \
        __builtin_amdgcn_s_setprio(1);                                                  \
        _Pragma("unroll")                                                               \
        for (int m = 0; m < 4; ++m) {                                                   \
            int rowa = (wr + m * 16 + fr) << 7;                                         \
            bf16x8 a0 = *reinterpret_cast<const bf16x8*>(ab + (rowa + koff0));          \
            bf16x8 a1 = *reinterpret_cast<const bf16x8*>(ab + (rowa + koff1));          \
            _Pragma("unroll")                                                           \
            for (int n = 0; n < 4; ++n) {                                               \
                acc[m][n] = __builtin_amdgcn_mfma_f32_16x16x32_bf16(a0, breg[P][n][0], acc[m][n], 0, 0, 0); \
                acc[m][n] = __builtin_amdgcn_mfma_f32_16x16x32_bf16(a1, breg[P][n][1], acc[m][n], 0, 0, 0); \
            }                                                                           \
        }                                                                               \
        __builtin_amdgcn_s_setprio(0);                                                  \
        if ((T) < NT - 2) {                                                             \
            asm volatile("s_waitcnt lgkmcnt(0)" ::: "memory");                          \
            __builtin_amdgcn_s_barrier();                                               \
            _Pragma("unroll")                                                           \
            for (int n = 0; n < 4; ++n)                                                 \
                _Pragma("unroll")                                                       \
                for (int ks = 0; ks < 2; ++ks)                                          \
                    breg[(P) ^ 1][n][ks] = *reinterpret_cast<const bf16x8*>(            \
                        bptr + ((size_t)n << 15) + ((size_t)(((T) + 1) * 2 + ks) << 9)); \
            MEMFENCE();                                                                 \
            const int nk = ((T) + 2) * 64;                                              \
            char* dA = lds + (P) * 16384 + wv * 1024;                                   \
            _Pragma("unroll")                                                           \
            for (int i = 0; i < 4; ++i) GLOAD16(srcA[i] + nk, dA + i * 4096);           \
            MEMFENCE();                                                                 \
        } else if ((T) == NT - 2) {                                                     \
            /* last B prefetch: registers only, no LDS hazard, no barrier */            \
            _Pragma("unroll")                                                           \
            for (int n = 0; n < 4; ++n)                                                 \
                _Pragma("unroll")                                                       \
                for (int ks = 0; ks < 2; ++ks)                                          \
                    breg[(P) ^ 1][n][ks] = *reinterpret_cast<const bf16x8*>(            \
                        bptr + ((size_t)n << 15) + ((size_t)(((T) + 1) * 2 + ks) << 9)); \
            MEMFENCE();                                                                 \
        }                                                                               \
    }

    for (int t = 0; t < NT; t += 2) {
        K_STEP(t,     0)
        K_STEP(t + 1, 1)
    }
#undef K_STEP

    // epilogue: (acc + bias) * coef, atomic combine (exactly 2 adds/element)
    const int rj = (lane >> 4) * 4;
    float bias_[4];
#pragma unroll
    for (int n = 0; n < 4; ++n)
        bias_[n] = bexp[(size_t)e * HD + cb + wc + n * 16 + fr];

#pragma unroll
    for (int m = 0; m < 4; ++m) {
        const int lr = wr + m * 16 + rj;
        int tok[4]; float cf[4];
#pragma unroll
        for (int j = 0; j < 4; ++j) {
            tok[j] = row_token[r0 + lr + j];
            cf[j]  = row_coef[r0 + lr + j];
        }
#pragma unroll
        for (int n = 0; n < 4; ++n) {
            const int f = cb + wc + n * 16 + fr;
#pragma unroll
            for (int j = 0; j < 4; ++j) {
                if (tok[j] >= 0)
                    atomicAdd(&out[(size_t)tok[j] * HD + f], (acc[m][n][j] + bias_[n]) * cf[j]);
            }
        }
    }
}

// ---------------------------------------------------------------------------
extern "C" void kernel_launch(void* const* d_in, const int* in_sizes, int n_in,
                              void* d_out, int out_size, void* d_ws, size_t ws_size,
                              hipStream_t stream)
{
    (void)in_sizes; (void)n_in; (void)out_size; (void)ws_size;

    const float* x  = (const float*)d_in[0];
    const float* Wg = (const float*)d_in[1];
    const float* bg = (const float*)d_in[2];
    const float* W  = (const float*)d_in[3];
    const float* b  = (const float*)d_in[4];

    float* out    = (float*)d_out;
    float* logits = out + (size_t)T_TOK * HD;

    // workspace layout (~101 MB; proven sufficient)
    char* p = (char*)d_ws;
    int*   cnt       = (int*)p;   p += NE * 4;
    int*   cursor    = (int*)p;   p += NE * 4;
    int*   ntiles    = (int*)p;   p += 8;
    int*   tile_exp  = (int*)p;   p += MAXT * 4;
    int*   tile_row0 = (int*)p;   p += MAXT * 4;
    int*   tok_exp   = (int*)p;   p += T_TOK * 2 * 4;
    float* tok_w     = (float*)p; p += T_TOK * 2 * 4;
    int*   row_token = (int*)p;   p += RMAX * 4;
    float* row_coef  = (float*)p; p += RMAX * 4;
    p = (char*)(((size_t)p + 255) & ~(size_t)255);
    __bf16* xb  = (__bf16*)p;     p += (size_t)T_TOK * HD * 2;     // 33.5 MB
    __bf16* Wt2 = (__bf16*)p;     p += (size_t)NE * HD * HD * 2;   // 67.1 MB

    hipMemsetAsync(cnt, 0, NE * 4, stream);
    hipMemsetAsync(row_token, 0xFF, RMAX * 4, stream);             // -1 fill
    hipMemsetAsync(out, 0, (size_t)T_TOK * HD * sizeof(float), stream);

    router_cvt_kernel<<<T_TOK / 4, 256, 0, stream>>>(x, Wg, bg, logits,
                                                     tok_exp, tok_w, xb, cnt);
    wt2_kernel<<<dim3(HD / 64, HD / 64, NE), 256, 0, stream>>>(W, Wt2);
    scan_kernel<<<1, 64, 0, stream>>>(cnt, cursor, tile_exp, tile_row0, ntiles);
    scatter_kernel<<<T_TOK * 2 / 256, 256, 0, stream>>>(tok_exp, tok_w, cursor,
                                                        row_token, row_coef);

    dim3 grid(HD / BN, MAXT);
    moe_gemm_128<<<grid, 256, 0, stream>>>(xb, Wt2, b, tile_exp, tile_row0, ntiles,
                                           row_token, row_coef, out);
}

// Round 16
// 332.829 us; speedup vs baseline: 1.0669x; 1.0669x over previous
//
#include <hip/hip_runtime.h>
#include <math.h>

#define T_TOK 8192
#define HD    2048
#define NE    8
#define BM    128
#define BN    128
#define NT    (HD / 64)      // 32 K-tiles
#define MAXT  136            // max row-tiles: 16384/128 + 8 pad tiles
#define RMAX  17408          // 136 * 128

typedef __bf16 bf16x4 __attribute__((ext_vector_type(4)));
typedef __bf16 bf16x8 __attribute__((ext_vector_type(8)));
typedef float  f32x4  __attribute__((ext_vector_type(4)));

// 16B async global->LDS. LDS dest is wave-uniform base + lane*16 (linear);
// per-lane GLOBAL source carries the swizzle (rule 21: linear dest +
// inverse-swizzled source + swizzled read).
#define GLOAD16(src, dst)                                                              \
    __builtin_amdgcn_global_load_lds((__attribute__((address_space(1))) void*)(src),   \
                                     (__attribute__((address_space(3))) void*)(dst),   \
                                     16, 0, 0)

// ---------------------------------------------------------------------------
// Router + x->bf16 + expert histogram fused. 4 tokens/block; LDS bins then
// 8 global atomics per block (16K total spread over 2048 blocks, no hot-spot).
// ---------------------------------------------------------------------------
__global__ __launch_bounds__(256) void router_cvt_kernel(
    const float* __restrict__ x, const float* __restrict__ Wg,
    const float* __restrict__ bg, float* __restrict__ logits_out,
    int* __restrict__ tok_exp, float* __restrict__ tok_w,
    __bf16* __restrict__ xb, int* __restrict__ cnt)
{
    __shared__ int hbin[NE];
    const int lane = threadIdx.x & 63;
    const int wv   = threadIdx.x >> 6;
    const int t    = blockIdx.x * 4 + wv;
    const float* xr  = x  + (size_t)t * HD;
    __bf16*      xbr = xb + (size_t)t * HD;

    if (threadIdx.x < NE) hbin[threadIdx.x] = 0;
    __syncthreads();

    float acc[8] = {0.f,0.f,0.f,0.f,0.f,0.f,0.f,0.f};
#pragma unroll
    for (int j = 0; j < 8; ++j) {
        const int h0 = j * 256 + lane * 4;
        float4 xv = *reinterpret_cast<const float4*>(xr + h0);
        bf16x4 bv;
        bv[0] = (__bf16)xv.x; bv[1] = (__bf16)xv.y;
        bv[2] = (__bf16)xv.z; bv[3] = (__bf16)xv.w;
        *reinterpret_cast<bf16x4*>(xbr + h0) = bv;

        const float4* wg = reinterpret_cast<const float4*>(Wg + (size_t)h0 * NE);
        float xs[4] = {xv.x, xv.y, xv.z, xv.w};
#pragma unroll
        for (int r = 0; r < 4; ++r) {
            float4 wa = wg[r * 2], wb = wg[r * 2 + 1];
            acc[0] += xs[r] * wa.x; acc[1] += xs[r] * wa.y;
            acc[2] += xs[r] * wa.z; acc[3] += xs[r] * wa.w;
            acc[4] += xs[r] * wb.x; acc[5] += xs[r] * wb.y;
            acc[6] += xs[r] * wb.z; acc[7] += xs[r] * wb.w;
        }
    }
#pragma unroll
    for (int off = 32; off; off >>= 1) {
#pragma unroll
        for (int e = 0; e < 8; ++e) acc[e] += __shfl_xor(acc[e], off);
    }
    if (lane == 0) {
        float lg[8];
#pragma unroll
        for (int e = 0; e < 8; ++e) lg[e] = acc[e] + bg[e];
        float4* lo = reinterpret_cast<float4*>(logits_out + (size_t)t * NE);
        lo[0] = make_float4(lg[0], lg[1], lg[2], lg[3]);
        lo[1] = make_float4(lg[4], lg[5], lg[6], lg[7]);
        int i0 = 0;
        for (int e = 1; e < 8; ++e) if (lg[e] > lg[i0]) i0 = e;
        int i1 = (i0 == 0) ? 1 : 0;
        for (int e = 0; e < 8; ++e) if (e != i0 && lg[e] > lg[i1]) i1 = e;
        float d = expf(lg[i1] - lg[i0]);
        float inv = 1.0f / (1.0f + d);
        tok_exp[t * 2]     = i0;
        tok_exp[t * 2 + 1] = i1;
        tok_w[t * 2]       = inv;
        tok_w[t * 2 + 1]   = d * inv;
        atomicAdd(&hbin[i0], 1);
        atomicAdd(&hbin[i1], 1);
    }
    __syncthreads();
    if (threadIdx.x < NE && hbin[threadIdx.x] > 0)
        atomicAdd(&cnt[threadIdx.x], hbin[threadIdx.x]);
}

// ---------------------------------------------------------------------------
// W[e][k][f] fp32 -> Wt[e][f][k] bf16. 64x64 tile via padded fp32 LDS [64][65].
// ---------------------------------------------------------------------------
__global__ __launch_bounds__(256) void wt_kernel(const float* __restrict__ W,
                                                 __bf16* __restrict__ Wt)
{
    const int e  = blockIdx.z;
    const int k0 = blockIdx.y * 64;
    const int f0 = blockIdx.x * 64;
    __shared__ float T[64][65];

    const int t  = threadIdx.x;
    const int fi = (t & 15) * 4;
    const int kb = t >> 4;
    const float* src = W + (size_t)e * HD * HD + (size_t)(k0 + kb) * HD + f0 + fi;
#pragma unroll
    for (int j = 0; j < 4; ++j) {
        float4 v = *reinterpret_cast<const float4*>(src + (size_t)j * 16 * HD);
        int k = kb + j * 16;
        T[k][fi + 0] = v.x;
        T[k][fi + 1] = v.y;
        T[k][fi + 2] = v.z;
        T[k][fi + 3] = v.w;
    }
    __syncthreads();
    const int f  = t >> 2;
    const int kc = (t & 3) * 16;
    bf16x8 o0, o1;
#pragma unroll
    for (int j = 0; j < 8; ++j) o0[j] = (__bf16)T[kc + j][f];
#pragma unroll
    for (int j = 0; j < 8; ++j) o1[j] = (__bf16)T[kc + 8 + j][f];
    __bf16* dst = Wt + (size_t)e * HD * HD + (size_t)(f0 + f) * HD + k0 + kc;
    *reinterpret_cast<bf16x8*>(dst)     = o0;
    *reinterpret_cast<bf16x8*>(dst + 8) = o1;
}

// ---------------------------------------------------------------------------
// Scan: per-expert offsets padded to 128, tile table, init cursors.
// ---------------------------------------------------------------------------
__global__ void scan_kernel(const int* __restrict__ cnt, int* __restrict__ cursor,
                            int* __restrict__ tile_exp, int* __restrict__ tile_row0,
                            int* __restrict__ ntiles)
{
    if (threadIdx.x == 0) {
        int off = 0, nt = 0;
        for (int e = 0; e < NE; ++e) {
            cursor[e] = off;
            int c = cnt[e];
            int tiles = (c + 127) >> 7;
            for (int i = 0; i < tiles; ++i) {
                tile_exp[nt]  = e;
                tile_row0[nt] = off + (i << 7);
                ++nt;
            }
            off += tiles << 7;
        }
        *ntiles = nt;
    }
}

// ---------------------------------------------------------------------------
// Scatter: per-block LDS ranks + ONE cursor reservation per expert per block.
// Order within bucket nondeterministic but results order-independent.
// ---------------------------------------------------------------------------
__global__ __launch_bounds__(256) void scatter_kernel(
    const int* __restrict__ tok_exp, const float* __restrict__ tok_w,
    int* __restrict__ cursor, int* __restrict__ row_token, float* __restrict__ row_coef)
{
    __shared__ int lcnt[NE];
    __shared__ int lbase[NE];
    const int tid = threadIdx.x;
    if (tid < NE) lcnt[tid] = 0;
    __syncthreads();
    const int s = blockIdx.x * 256 + tid;
    const int e = tok_exp[s];
    const int r = atomicAdd(&lcnt[e], 1);          // LDS atomic (fast)
    __syncthreads();
    if (tid < NE) lbase[tid] = atomicAdd(&cursor[tid], lcnt[tid]);
    __syncthreads();
    const int pos = lbase[e] + r;
    row_token[pos] = s >> 1;                        // slot -> token
    row_coef[pos]  = tok_w[s];
}

// ---------------------------------------------------------------------------
// Grouped GEMM — FINAL configuration (best measured, reproduced twice:
// GEMM 215-217 µs, MfmaUtil 28, total 334 µs): 128x128 tile, BK=64,
// 4 waves (2x2, 64x64 each), double-buffered LDS (64 KB) -> 2 blocks/CU.
// Counted-vmcnt pipeline: prologue stages tiles 0,1; per K-step:
//   s_waitcnt vmcnt(8) -> barrier -> ds_read + 32 MFMA -> lgkmcnt(0)
//   -> barrier -> issue tile t+2 into the buffer just read.
// Bracketed and rejected (15 rounds): drain-2-barrier (R3), 4-phase x2
// (R6), m201-faithful 4-phase (R7), single-drain (R9), B-direct scattered
// (R11), B fragment-major direct (R15), BK=32 @4 blocks (R13), 3 blocks
// (R15), 256^2 tile (R4/R8), T1 XCD remap (neutral, R8).
// ---------------------------------------------------------------------------
__global__ __launch_bounds__(256, 2) void moe_gemm_128(
    const __bf16* __restrict__ xb, const __bf16* __restrict__ Wt,
    const float* __restrict__ bexp,
    const int* __restrict__ tile_exp, const int* __restrict__ tile_row0,
    const int* __restrict__ ntiles_p, const int* __restrict__ row_token,
    const float* __restrict__ row_coef, float* __restrict__ out)
{
    const int rt = blockIdx.y;
    if (rt >= *ntiles_p) return;
    const int e  = tile_exp[rt];
    const int r0 = tile_row0[rt];
    const int cb = blockIdx.x * BN;

    // buf c at c*32768: A [128][64]bf16 (16K) then B [128][64]bf16 (16K)
    __shared__ __align__(16) char lds[65536];

    const int tid  = threadIdx.x;
    const int lane = tid & 63;
    const int wv   = tid >> 6;          // 0..3
    const int wr   = (wv >> 1) * 64;    // wave row base
    const int wc   = (wv & 1) * 64;     // wave col base

    // source column pre-swizzled so linear LDS dest + swizzled read = no conflicts
    const int colS = ((((tid & 7) * 16) ^ (((tid >> 3) & 7) << 4))) >> 1;  // bf16 elems

    const __bf16* srcA[4];
    const __bf16* srcB[4];
#pragma unroll
    for (int i = 0; i < 4; ++i) {
        int gr  = i * 32 + (tid >> 3);
        int tok = row_token[r0 + gr];
        if (tok < 0) tok = 0;           // pad rows: arbitrary data, discarded later
        srcA[i] = xb + (size_t)tok * HD + colS;
        srcB[i] = Wt + ((size_t)e << 22) + (size_t)(cb + gr) * HD + colS;
    }

    f32x4 acc[4][4];
#pragma unroll
    for (int m = 0; m < 4; ++m)
#pragma unroll
        for (int n = 0; n < 4; ++n) acc[m][n] = (f32x4){0.f, 0.f, 0.f, 0.f};

    const int fr    = lane & 15;
    const int swz   = (lane & 7) << 4;
    const int koff0 = (((lane >> 4) * 16)      ) ^ swz;   // ks=0 k-byte, swizzled
    const int koff1 = (((lane >> 4) * 16) + 64 ) ^ swz;   // ks=1

    // prologue: stage K-tiles 0 and 1 (16 loads in flight per thread)
    {
        char* d0 = lds + wv * 1024;
        char* d1 = d0 + 32768;
#pragma unroll
        for (int i = 0; i < 4; ++i) GLOAD16(srcA[i], d0 + i * 4096);
#pragma unroll
        for (int i = 0; i < 4; ++i) GLOAD16(srcB[i], d0 + 16384 + i * 4096);
#pragma unroll
        for (int i = 0; i < 4; ++i) GLOAD16(srcA[i] + 64, d1 + i * 4096);
#pragma unroll
        for (int i = 0; i < 4; ++i) GLOAD16(srcB[i] + 64, d1 + 16384 + i * 4096);
    }

#pragma unroll 2
    for (int t = 0; t < NT; ++t) {
        if (t < NT - 1) { asm volatile("s_waitcnt vmcnt(8)" ::: "memory"); }
        else            { asm volatile("s_waitcnt vmcnt(0)" ::: "memory"); }
        __builtin_amdgcn_s_barrier();

        const char* ab = lds + (t & 1) * 32768;
        const char* bb = ab + 16384;

        bf16x8 bfr0[4], bfr1[4];
#pragma unroll
        for (int n = 0; n < 4; ++n) {
            int rowb = (wc + n * 16 + fr) << 7;
            bfr0[n] = *reinterpret_cast<const bf16x8*>(bb + (rowb + koff0));
            bfr1[n] = *reinterpret_cast<const bf16x8*>(bb + (rowb + koff1));
        }
        __builtin_amdgcn_s_setprio(1);
#pragma unroll
        for (int m = 0; m < 4; ++m) {
            int rowa = (wr + m * 16 + fr) << 7;
            bf16x8 a0 = *reinterpret_cast<const bf16x8*>(ab + (rowa + koff0));
            bf16x8 a1 = *reinterpret_cast<const bf16x8*>(ab + (rowa + koff1));
#pragma unroll
            for (int n = 0; n < 4; ++n) {
                acc[m][n] = __builtin_amdgcn_mfma_f32_16x16x32_bf16(a0, bfr0[n], acc[m][n], 0, 0, 0);
                acc[m][n] = __builtin_amdgcn_mfma_f32_16x16x32_bf16(a1, bfr1[n], acc[m][n], 0, 0, 0);
            }
        }
        __builtin_amdgcn_s_setprio(0);

        if (t < NT - 2) {
            asm volatile("s_waitcnt lgkmcnt(0)" ::: "memory");
            __builtin_amdgcn_s_barrier();
            const int nk = (t + 2) * 64;
            char* dA = lds + (t & 1) * 32768 + wv * 1024;
#pragma unroll
            for (int i = 0; i < 4; ++i) GLOAD16(srcA[i] + nk, dA + i * 4096);
#pragma unroll
            for (int i = 0; i < 4; ++i) GLOAD16(srcB[i] + nk, dA + 16384 + i * 4096);
        }
    }

    // epilogue: (acc + bias) * coef, atomic combine (exactly 2 adds/element)
    const int rj = (lane >> 4) * 4;
    float bias_[4];
#pragma unroll
    for (int n = 0; n < 4; ++n)
        bias_[n] = bexp[(size_t)e * HD + cb + wc + n * 16 + fr];

#pragma unroll
    for (int m = 0; m < 4; ++m) {
        const int lr = wr + m * 16 + rj;
        int tok[4]; float cf[4];
#pragma unroll
        for (int j = 0; j < 4; ++j) {
            tok[j] = row_token[r0 + lr + j];
            cf[j]  = row_coef[r0 + lr + j];
        }
#pragma unroll
        for (int n = 0; n < 4; ++n) {
            const int f = cb + wc + n * 16 + fr;
#pragma unroll
            for (int j = 0; j < 4; ++j) {
                if (tok[j] >= 0)
                    atomicAdd(&out[(size_t)tok[j] * HD + f], (acc[m][n][j] + bias_[n]) * cf[j]);
            }
        }
    }
}

// ---------------------------------------------------------------------------
extern "C" void kernel_launch(void* const* d_in, const int* in_sizes, int n_in,
                              void* d_out, int out_size, void* d_ws, size_t ws_size,
                              hipStream_t stream)
{
    (void)in_sizes; (void)n_in; (void)out_size; (void)ws_size;

    const float* x  = (const float*)d_in[0];
    const float* Wg = (const float*)d_in[1];
    const float* bg = (const float*)d_in[2];
    const float* W  = (const float*)d_in[3];
    const float* b  = (const float*)d_in[4];

    float* out    = (float*)d_out;
    float* logits = out + (size_t)T_TOK * HD;

    // workspace layout (~101 MB; proven sufficient)
    char* p = (char*)d_ws;
    int*   cnt       = (int*)p;   p += NE * 4;
    int*   cursor    = (int*)p;   p += NE * 4;
    int*   ntiles    = (int*)p;   p += 8;
    int*   tile_exp  = (int*)p;   p += MAXT * 4;
    int*   tile_row0 = (int*)p;   p += MAXT * 4;
    int*   tok_exp   = (int*)p;   p += T_TOK * 2 * 4;
    float* tok_w     = (float*)p; p += T_TOK * 2 * 4;
    int*   row_token = (int*)p;   p += RMAX * 4;
    float* row_coef  = (float*)p; p += RMAX * 4;
    p = (char*)(((size_t)p + 255) & ~(size_t)255);
    __bf16* xb = (__bf16*)p;      p += (size_t)T_TOK * HD * 2;     // 33.5 MB
    __bf16* Wt = (__bf16*)p;      p += (size_t)NE * HD * HD * 2;   // 67.1 MB

    hipMemsetAsync(cnt, 0, NE * 4, stream);
    hipMemsetAsync(row_token, 0xFF, RMAX * 4, stream);             // -1 fill
    hipMemsetAsync(out, 0, (size_t)T_TOK * HD * sizeof(float), stream);

    router_cvt_kernel<<<T_TOK / 4, 256, 0, stream>>>(x, Wg, bg, logits,
                                                     tok_exp, tok_w, xb, cnt);
    wt_kernel<<<dim3(HD / 64, HD / 64, NE), 256, 0, stream>>>(W, Wt);
    scan_kernel<<<1, 64, 0, stream>>>(cnt, cursor, tile_exp, tile_row0, ntiles);
    scatter_kernel<<<T_TOK * 2 / 256, 256, 0, stream>>>(tok_exp, tok_w, cursor,
                                                        row_token, row_coef);

    dim3 grid(HD / BN, MAXT);
    moe_gemm_128<<<grid, 256, 0, stream>>>(xb, Wt, b, tile_exp, tile_row0, ntiles,
                                           row_token, row_coef, out);
}